// Round 1
// baseline (1677.574 us; speedup 1.0000x reference)
//
#include <hip/hip_runtime.h>

// CLF_K_QP_Net: B=65536, N=16, H=128, NC=2.
// 4 lanes per batch element (owner o = lane&3 owns hidden slice [32o, 32o+32)).
// All activations live in registers; cross-lane combine via __shfl_xor(1|2).

__device__ __forceinline__ float fast_tanh(float v) {
    v = fminf(15.0f, fmaxf(-15.0f, v));
    float e = __expf(2.0f * v);
    return (e - 1.0f) / (e + 1.0f);
}

// K-net: K[n] = sum_h Kb_w[n][h] * tanh(Ka_b[h] + Ka_w[h]·x)   (bias added by caller)
__device__ __forceinline__ void knet(const float* __restrict__ Ka_w,
                                     const float* __restrict__ Ka_b,
                                     const float* __restrict__ Kb_w,
                                     const float xr[16], int kb, float K[16]) {
    float a[32];
#pragma unroll
    for (int j = 0; j < 32; ++j) {
        const float* wr = Ka_w + (kb + j) * 16;
        float z0 = Ka_b[kb + j], z1 = 0.f;
#pragma unroll
        for (int n = 0; n < 16; n += 2) {
            z0 = fmaf(wr[n], xr[n], z0);
            z1 = fmaf(wr[n + 1], xr[n + 1], z1);
        }
        a[j] = fast_tanh(z0 + z1);
    }
#pragma unroll
    for (int n = 0; n < 16; ++n) {
        const float* wr = Kb_w + n * 128 + kb;
        float c0 = 0.f, c1 = 0.f;
#pragma unroll
        for (int j = 0; j < 32; j += 2) {
            c0 = fmaf(wr[j], a[j], c0);
            c1 = fmaf(wr[j + 1], a[j + 1], c1);
        }
        float acc = c0 + c1;
        acc += __shfl_xor(acc, 1);
        acc += __shfl_xor(acc, 2);
        K[n] = acc;
    }
}

__global__ void clf_fused_kernel(
    const float* __restrict__ x,
    const float* __restrict__ V1_w, const float* __restrict__ V1_b,
    const float* __restrict__ V2_w, const float* __restrict__ V2_b,
    const float* __restrict__ K1a_w, const float* __restrict__ K1a_b,
    const float* __restrict__ K1b_w, const float* __restrict__ K1b_b,
    const float* __restrict__ K2a_w, const float* __restrict__ K2a_b,
    const float* __restrict__ K2b_w, const float* __restrict__ K2b_b,
    const float* __restrict__ A_dyn, const float* __restrict__ B_dyn,
    const float* __restrict__ x_goal, const float* __restrict__ u_eq,
    float* __restrict__ out, int B) {
    const int tid = blockIdx.x * blockDim.x + threadIdx.x;
    if (tid == 0) out[2 * B] = 0.0f;  // relaxation = zeros((1,))
    const int b = tid >> 2;
    if (b >= B) return;
    const int o = tid & 3;
    const int kb = o << 5;  // owned slice base in [0,128)

    // ---- x (all 16, per lane) ----
    float xr[16];
#pragma unroll
    for (int q = 0; q < 4; ++q) {
        float4 v = *reinterpret_cast<const float4*>(x + b * 16 + 4 * q);
        xr[4 * q + 0] = v.x; xr[4 * q + 1] = v.y;
        xr[4 * q + 2] = v.z; xr[4 * q + 3] = v.w;
    }

    // ---- t1 (owned 32 of 128) ----
    float t1[32];
#pragma unroll
    for (int j = 0; j < 32; ++j) {
        const float* wr = V1_w + (kb + j) * 16;
        float z0 = V1_b[kb + j], z1 = 0.f;
#pragma unroll
        for (int n = 0; n < 16; n += 2) {
            z0 = fmaf(wr[n], xr[n], z0);
            z1 = fmaf(wr[n + 1], xr[n + 1], z1);
        }
        t1[j] = fast_tanh(z0 + z1);
    }

    // ---- pass over h: t2, V, and w[k] = sum_h s2[h]*V2_w[h][k] (owned k) ----
    float w[32];
#pragma unroll
    for (int j = 0; j < 32; ++j) w[j] = 0.f;
    float Vacc = 0.f;
    for (int h = 0; h < 128; ++h) {
        const float* vrow = V2_w + h * 128 + kb;
        float rv[32];
#pragma unroll
        for (int q = 0; q < 8; ++q) {
            float4 v = *reinterpret_cast<const float4*>(vrow + 4 * q);
            rv[4 * q + 0] = v.x; rv[4 * q + 1] = v.y;
            rv[4 * q + 2] = v.z; rv[4 * q + 3] = v.w;
        }
        float z0 = 0.f, z1 = 0.f;
#pragma unroll
        for (int j = 0; j < 32; j += 2) {
            z0 = fmaf(rv[j], t1[j], z0);
            z1 = fmaf(rv[j + 1], t1[j + 1], z1);
        }
        float zp = z0 + z1;
        zp += __shfl_xor(zp, 1);
        zp += __shfl_xor(zp, 2);
        float t2 = fast_tanh(zp + V2_b[h]);
        Vacc = fmaf(0.5f * t2, t2, Vacc);
        float s2 = t2 * (1.0f - t2 * t2);
#pragma unroll
        for (int j = 0; j < 32; ++j) w[j] = fmaf(s2, rv[j], w[j]);
    }

    // ---- gV[n] = sum_k w[k]*(1-t1[k]^2)*V1_w[k][n] ----
    float gV[16];
#pragma unroll
    for (int n = 0; n < 16; ++n) gV[n] = 0.f;
#pragma unroll
    for (int j = 0; j < 32; ++j) {
        float c = w[j] * (1.0f - t1[j] * t1[j]);
        const float* wr = V1_w + (kb + j) * 16;
#pragma unroll
        for (int n = 0; n < 16; ++n) gV[n] = fmaf(c, wr[n], gV[n]);
    }
#pragma unroll
    for (int n = 0; n < 16; ++n) {
        gV[n] += __shfl_xor(gV[n], 1);
        gV[n] += __shfl_xor(gV[n], 2);
    }

    // ---- K nets ----
    float K1[16], K2[16];
    knet(K1a_w, K1a_b, K1b_w, xr, kb, K1);
    knet(K2a_w, K2a_b, K2b_w, xr, kb, K2);

    // ---- epilogue ----
    float u0 = u_eq[0], u1 = u_eq[1];
#pragma unroll
    for (int n = 0; n < 16; ++n) {
        float dxn = xr[n] - x_goal[n];
        u0 = fmaf(-(K1[n] + K1b_b[n]), dxn, u0);
        u1 = fmaf(-(K2[n] + K2b_b[n]), dxn, u1);
    }
    // F = gV · (A_dyn @ x)
    float F = 0.f;
#pragma unroll
    for (int n = 0; n < 16; ++n) {
        const float* ar = A_dyn + n * 16;
        float f0 = 0.f, f1 = 0.f;
#pragma unroll
        for (int m = 0; m < 16; m += 2) {
            f0 = fmaf(ar[m], xr[m], f0);
            f1 = fmaf(ar[m + 1], xr[m + 1], f1);
        }
        F = fmaf(gV[n], f0 + f1, F);
    }
    // L_g_V = gV @ B_dyn  (NC=2)
    float Lg0 = 0.f, Lg1 = 0.f;
#pragma unroll
    for (int n = 0; n < 16; ++n) {
        Lg0 = fmaf(gV[n], B_dyn[2 * n + 0], Lg0);
        Lg1 = fmaf(gV[n], B_dyn[2 * n + 1], Lg1);
    }
    float G = fmaf(Lg0, u0, fmaf(Lg1, u1, Vacc));  // LgVu + lambda*V
    float Vdot = 0.5f * (fmaxf(F + G, 0.f) + fmaxf(fmaf(1.2f, F, G), 0.f));

    if (o == 0) {
        // outputs flat: u (2B) | relaxation (1) | V (B) | Vdot (B)
        float2 uo; uo.x = u0; uo.y = u1;
        *reinterpret_cast<float2*>(out + 2 * b) = uo;
        out[2 * B + 1 + b] = Vacc;
        out[3 * B + 1 + b] = Vdot;
    }
}

extern "C" void kernel_launch(void* const* d_in, const int* in_sizes, int n_in,
                              void* d_out, int out_size, void* d_ws, size_t ws_size,
                              hipStream_t stream) {
    const float* x     = (const float*)d_in[0];
    const float* V1_w  = (const float*)d_in[1];
    const float* V1_b  = (const float*)d_in[2];
    const float* V2_w  = (const float*)d_in[3];
    const float* V2_b  = (const float*)d_in[4];
    const float* K1a_w = (const float*)d_in[5];
    const float* K1a_b = (const float*)d_in[6];
    const float* K1b_w = (const float*)d_in[7];
    const float* K1b_b = (const float*)d_in[8];
    const float* K2a_w = (const float*)d_in[9];
    const float* K2a_b = (const float*)d_in[10];
    const float* K2b_w = (const float*)d_in[11];
    const float* K2b_b = (const float*)d_in[12];
    const float* A_dyn = (const float*)d_in[13];
    const float* B_dyn = (const float*)d_in[14];
    const float* x_goal= (const float*)d_in[15];
    const float* u_eq  = (const float*)d_in[16];
    float* out = (float*)d_out;

    const int B = in_sizes[0] / 16;          // 65536
    const int threads = 256;
    const int total = B * 4;                 // 4 lanes per element
    const int blocks = (total + threads - 1) / threads;
    clf_fused_kernel<<<blocks, threads, 0, stream>>>(
        x, V1_w, V1_b, V2_w, V2_b, K1a_w, K1a_b, K1b_w, K1b_b,
        K2a_w, K2a_b, K2b_w, K2b_b, A_dyn, B_dyn, x_goal, u_eq, out, B);
}

// Round 2
// 1296.255 us; speedup vs baseline: 1.2942x; 1.2942x over previous
//
#include <hip/hip_runtime.h>

// CLF_K_QP_Net: B=65536, N=16, H=128, NC=2.
// 4 lanes per batch element (owner o = lane&3 owns hidden slice [32o, 32o+32)).
// All activations live in registers; cross-lane combine via __shfl_xor(1|2).
// __launch_bounds__(256,2): VGPR cap 256 — without it hipcc capped at 64 VGPRs
// and spilled ~2.6 GB/launch to scratch (R1: 1677us, VALUBusy 5%).

__device__ __forceinline__ float fast_tanh(float v) {
    v = fminf(15.0f, fmaxf(-15.0f, v));
    float e = __expf(2.0f * v);
    return (e - 1.0f) / (e + 1.0f);
}

// K-net: K[n] = sum_h Kb_w[n][h] * tanh(Ka_b[h] + Ka_w[h]·x)   (bias added by caller)
__device__ __forceinline__ void knet(const float* __restrict__ Ka_w,
                                     const float* __restrict__ Ka_b,
                                     const float* __restrict__ Kb_w,
                                     const float xr[16], int kb, float K[16]) {
    float a[32];
#pragma unroll
    for (int j = 0; j < 32; ++j) {
        const float* wr = Ka_w + (kb + j) * 16;
        float z0 = Ka_b[kb + j], z1 = 0.f;
#pragma unroll
        for (int n = 0; n < 16; n += 2) {
            z0 = fmaf(wr[n], xr[n], z0);
            z1 = fmaf(wr[n + 1], xr[n + 1], z1);
        }
        a[j] = fast_tanh(z0 + z1);
    }
#pragma unroll
    for (int n = 0; n < 16; ++n) {
        const float* wr = Kb_w + n * 128 + kb;
        float c0 = 0.f, c1 = 0.f;
#pragma unroll
        for (int j = 0; j < 32; j += 2) {
            c0 = fmaf(wr[j], a[j], c0);
            c1 = fmaf(wr[j + 1], a[j + 1], c1);
        }
        float acc = c0 + c1;
        acc += __shfl_xor(acc, 1);
        acc += __shfl_xor(acc, 2);
        K[n] = acc;
    }
}

__global__ void __launch_bounds__(256, 2) clf_fused_kernel(
    const float* __restrict__ x,
    const float* __restrict__ V1_w, const float* __restrict__ V1_b,
    const float* __restrict__ V2_w, const float* __restrict__ V2_b,
    const float* __restrict__ K1a_w, const float* __restrict__ K1a_b,
    const float* __restrict__ K1b_w, const float* __restrict__ K1b_b,
    const float* __restrict__ K2a_w, const float* __restrict__ K2a_b,
    const float* __restrict__ K2b_w, const float* __restrict__ K2b_b,
    const float* __restrict__ A_dyn, const float* __restrict__ B_dyn,
    const float* __restrict__ x_goal, const float* __restrict__ u_eq,
    float* __restrict__ out, int B) {
    const int tid = blockIdx.x * blockDim.x + threadIdx.x;
    if (tid == 0) out[2 * B] = 0.0f;  // relaxation = zeros((1,))
    const int b = tid >> 2;
    if (b >= B) return;
    const int o = tid & 3;
    const int kb = o << 5;  // owned slice base in [0,128)

    // ---- x (all 16, per lane) ----
    float xr[16];
#pragma unroll
    for (int q = 0; q < 4; ++q) {
        float4 v = *reinterpret_cast<const float4*>(x + b * 16 + 4 * q);
        xr[4 * q + 0] = v.x; xr[4 * q + 1] = v.y;
        xr[4 * q + 2] = v.z; xr[4 * q + 3] = v.w;
    }

    // ---- t1 (owned 32 of 128) ----
    float t1[32];
#pragma unroll
    for (int j = 0; j < 32; ++j) {
        const float* wr = V1_w + (kb + j) * 16;
        float z0 = V1_b[kb + j], z1 = 0.f;
#pragma unroll
        for (int n = 0; n < 16; n += 2) {
            z0 = fmaf(wr[n], xr[n], z0);
            z1 = fmaf(wr[n + 1], xr[n + 1], z1);
        }
        t1[j] = fast_tanh(z0 + z1);
    }

    // ---- pass over h: t2, V, and w[k] = sum_h s2[h]*V2_w[h][k] (owned k) ----
    float w[32];
#pragma unroll
    for (int j = 0; j < 32; ++j) w[j] = 0.f;
    float Vacc = 0.f;
    for (int h = 0; h < 128; ++h) {
        const float* vrow = V2_w + h * 128 + kb;
        float rv[32];
#pragma unroll
        for (int q = 0; q < 8; ++q) {
            float4 v = *reinterpret_cast<const float4*>(vrow + 4 * q);
            rv[4 * q + 0] = v.x; rv[4 * q + 1] = v.y;
            rv[4 * q + 2] = v.z; rv[4 * q + 3] = v.w;
        }
        float z0 = 0.f, z1 = 0.f;
#pragma unroll
        for (int j = 0; j < 32; j += 2) {
            z0 = fmaf(rv[j], t1[j], z0);
            z1 = fmaf(rv[j + 1], t1[j + 1], z1);
        }
        float zp = z0 + z1;
        zp += __shfl_xor(zp, 1);
        zp += __shfl_xor(zp, 2);
        float t2 = fast_tanh(zp + V2_b[h]);
        Vacc = fmaf(0.5f * t2, t2, Vacc);
        float s2 = t2 * (1.0f - t2 * t2);
#pragma unroll
        for (int j = 0; j < 32; ++j) w[j] = fmaf(s2, rv[j], w[j]);
    }

    // ---- gV[n] = sum_k w[k]*(1-t1[k]^2)*V1_w[k][n] ----
    float gV[16];
#pragma unroll
    for (int n = 0; n < 16; ++n) gV[n] = 0.f;
#pragma unroll
    for (int j = 0; j < 32; ++j) {
        float c = w[j] * (1.0f - t1[j] * t1[j]);
        const float* wr = V1_w + (kb + j) * 16;
#pragma unroll
        for (int n = 0; n < 16; ++n) gV[n] = fmaf(c, wr[n], gV[n]);
    }
#pragma unroll
    for (int n = 0; n < 16; ++n) {
        gV[n] += __shfl_xor(gV[n], 1);
        gV[n] += __shfl_xor(gV[n], 2);
    }

    // ---- K nets ----
    float K1[16], K2[16];
    knet(K1a_w, K1a_b, K1b_w, xr, kb, K1);
    knet(K2a_w, K2a_b, K2b_w, xr, kb, K2);

    // ---- epilogue ----
    float u0 = u_eq[0], u1 = u_eq[1];
#pragma unroll
    for (int n = 0; n < 16; ++n) {
        float dxn = xr[n] - x_goal[n];
        u0 = fmaf(-(K1[n] + K1b_b[n]), dxn, u0);
        u1 = fmaf(-(K2[n] + K2b_b[n]), dxn, u1);
    }
    // F = gV · (A_dyn @ x)
    float F = 0.f;
#pragma unroll
    for (int n = 0; n < 16; ++n) {
        const float* ar = A_dyn + n * 16;
        float f0 = 0.f, f1 = 0.f;
#pragma unroll
        for (int m = 0; m < 16; m += 2) {
            f0 = fmaf(ar[m], xr[m], f0);
            f1 = fmaf(ar[m + 1], xr[m + 1], f1);
        }
        F = fmaf(gV[n], f0 + f1, F);
    }
    // L_g_V = gV @ B_dyn  (NC=2)
    float Lg0 = 0.f, Lg1 = 0.f;
#pragma unroll
    for (int n = 0; n < 16; ++n) {
        Lg0 = fmaf(gV[n], B_dyn[2 * n + 0], Lg0);
        Lg1 = fmaf(gV[n], B_dyn[2 * n + 1], Lg1);
    }
    float G = fmaf(Lg0, u0, fmaf(Lg1, u1, Vacc));  // LgVu + lambda*V
    float Vdot = 0.5f * (fmaxf(F + G, 0.f) + fmaxf(fmaf(1.2f, F, G), 0.f));

    if (o == 0) {
        // outputs flat: u (2B) | relaxation (1) | V (B) | Vdot (B)
        float2 uo; uo.x = u0; uo.y = u1;
        *reinterpret_cast<float2*>(out + 2 * b) = uo;
        out[2 * B + 1 + b] = Vacc;
        out[3 * B + 1 + b] = Vdot;
    }
}

extern "C" void kernel_launch(void* const* d_in, const int* in_sizes, int n_in,
                              void* d_out, int out_size, void* d_ws, size_t ws_size,
                              hipStream_t stream) {
    const float* x     = (const float*)d_in[0];
    const float* V1_w  = (const float*)d_in[1];
    const float* V1_b  = (const float*)d_in[2];
    const float* V2_w  = (const float*)d_in[3];
    const float* V2_b  = (const float*)d_in[4];
    const float* K1a_w = (const float*)d_in[5];
    const float* K1a_b = (const float*)d_in[6];
    const float* K1b_w = (const float*)d_in[7];
    const float* K1b_b = (const float*)d_in[8];
    const float* K2a_w = (const float*)d_in[9];
    const float* K2a_b = (const float*)d_in[10];
    const float* K2b_w = (const float*)d_in[11];
    const float* K2b_b = (const float*)d_in[12];
    const float* A_dyn = (const float*)d_in[13];
    const float* B_dyn = (const float*)d_in[14];
    const float* x_goal= (const float*)d_in[15];
    const float* u_eq  = (const float*)d_in[16];
    float* out = (float*)d_out;

    const int B = in_sizes[0] / 16;          // 65536
    const int threads = 256;
    const int total = B * 4;                 // 4 lanes per element
    const int blocks = (total + threads - 1) / threads;
    clf_fused_kernel<<<blocks, threads, 0, stream>>>(
        x, V1_w, V1_b, V2_w, V2_b, K1a_w, K1a_b, K1b_w, K1b_b,
        K2a_w, K2a_b, K2b_w, K2b_b, A_dyn, B_dyn, x_goal, u_eq, out, B);
}

// Round 3
// 1074.408 us; speedup vs baseline: 1.5614x; 1.2065x over previous
//
#include <hip/hip_runtime.h>

// CLF_K_QP_Net: B=65536, N=16, H=128, NC=2.
// 8 lanes per batch element; lane o = tid&7 owns hidden slice [16o, 16o+16).
// Per-lane live set ~80 floats -> fits 128-VGPR budget (launch_bounds(256,4)),
// eliminating the scratch spills that dominated R1/R2 (1.2GB+ scratch traffic).
// Cross-lane combines: 3-stage __shfl_xor(1,2,4) within each 8-lane group.

__device__ __forceinline__ float fast_tanh(float v) {
    v = fminf(15.0f, fmaxf(-15.0f, v));
    float e = __expf(2.0f * v);
    return (e - 1.0f) / (e + 1.0f);
}

__device__ __forceinline__ float red8(float v) {
    v += __shfl_xor(v, 1);
    v += __shfl_xor(v, 2);
    v += __shfl_xor(v, 4);
    return v;
}

__global__ void __launch_bounds__(256, 4) clf_fused_kernel(
    const float* __restrict__ x,
    const float* __restrict__ V1_w, const float* __restrict__ V1_b,
    const float* __restrict__ V2_w, const float* __restrict__ V2_b,
    const float* __restrict__ K1a_w, const float* __restrict__ K1a_b,
    const float* __restrict__ K1b_w, const float* __restrict__ K1b_b,
    const float* __restrict__ K2a_w, const float* __restrict__ K2a_b,
    const float* __restrict__ K2b_w, const float* __restrict__ K2b_b,
    const float* __restrict__ A_dyn, const float* __restrict__ B_dyn,
    const float* __restrict__ x_goal, const float* __restrict__ u_eq,
    float* __restrict__ out, int B) {
    const int tid = blockIdx.x * blockDim.x + threadIdx.x;
    if (tid == 0) out[2 * B] = 0.0f;  // relaxation = zeros((1,))
    const int b = tid >> 3;
    if (b >= B) return;
    const int o = tid & 7;
    const int kb = o << 4;  // owned slice base in [0,128)

    // ---- x (all 16, per lane) ----
    float xr[16];
#pragma unroll
    for (int q = 0; q < 4; ++q) {
        float4 v = *reinterpret_cast<const float4*>(x + b * 16 + 4 * q);
        xr[4 * q + 0] = v.x; xr[4 * q + 1] = v.y;
        xr[4 * q + 2] = v.z; xr[4 * q + 3] = v.w;
    }

    // ---- t1 (owned 16 of 128) ----
    float t1[16];
#pragma unroll
    for (int j = 0; j < 16; ++j) {
        const float* wr = V1_w + (kb + j) * 16;
        float z0 = V1_b[kb + j], z1 = 0.f;
#pragma unroll
        for (int n = 0; n < 16; n += 2) {
            z0 = fmaf(wr[n], xr[n], z0);
            z1 = fmaf(wr[n + 1], xr[n + 1], z1);
        }
        t1[j] = fast_tanh(z0 + z1);
    }

    // ---- pass over h: t2, V, and w[k] = sum_h s2[h]*V2_w[h][k] (owned k) ----
    float w[16];
#pragma unroll
    for (int j = 0; j < 16; ++j) w[j] = 0.f;
    float Vacc = 0.f;
#pragma unroll 4
    for (int h = 0; h < 128; ++h) {
        const float* vrow = V2_w + h * 128 + kb;
        float rv[16];
#pragma unroll
        for (int q = 0; q < 4; ++q) {
            float4 v = *reinterpret_cast<const float4*>(vrow + 4 * q);
            rv[4 * q + 0] = v.x; rv[4 * q + 1] = v.y;
            rv[4 * q + 2] = v.z; rv[4 * q + 3] = v.w;
        }
        float z0 = 0.f, z1 = 0.f;
#pragma unroll
        for (int j = 0; j < 16; j += 2) {
            z0 = fmaf(rv[j], t1[j], z0);
            z1 = fmaf(rv[j + 1], t1[j + 1], z1);
        }
        float zp = red8(z0 + z1);
        float t2 = fast_tanh(zp + V2_b[h]);
        Vacc = fmaf(0.5f * t2, t2, Vacc);
        float s2 = t2 * (1.0f - t2 * t2);
#pragma unroll
        for (int j = 0; j < 16; ++j) w[j] = fmaf(s2, rv[j], w[j]);
    }

    // ---- gV[n] = sum_k w[k]*(1-t1[k]^2)*V1_w[k][n], reduced over 8 lanes ----
    float gV[16];
#pragma unroll
    for (int n = 0; n < 16; ++n) gV[n] = 0.f;
#pragma unroll
    for (int j = 0; j < 16; ++j) {
        float c = w[j] * (1.0f - t1[j] * t1[j]);
        const float* wr = V1_w + (kb + j) * 16;
#pragma unroll
        for (int n = 0; n < 16; ++n) gV[n] = fmaf(c, wr[n], gV[n]);
    }
#pragma unroll
    for (int n = 0; n < 16; ++n) gV[n] = red8(gV[n]);

    // ---- K nets, folded directly into u ----
    float u0 = u_eq[0], u1 = u_eq[1];
    {
        float a[16];
#pragma unroll
        for (int j = 0; j < 16; ++j) {
            const float* wr = K1a_w + (kb + j) * 16;
            float z0 = K1a_b[kb + j], z1 = 0.f;
#pragma unroll
            for (int n = 0; n < 16; n += 2) {
                z0 = fmaf(wr[n], xr[n], z0);
                z1 = fmaf(wr[n + 1], xr[n + 1], z1);
            }
            a[j] = fast_tanh(z0 + z1);
        }
#pragma unroll
        for (int n = 0; n < 16; ++n) {
            const float* wr = K1b_w + n * 128 + kb;
            float c0 = 0.f, c1 = 0.f;
#pragma unroll
            for (int j = 0; j < 16; j += 2) {
                c0 = fmaf(wr[j], a[j], c0);
                c1 = fmaf(wr[j + 1], a[j + 1], c1);
            }
            float K = red8(c0 + c1) + K1b_b[n];
            u0 = fmaf(-K, xr[n] - x_goal[n], u0);
        }
    }
    {
        float a[16];
#pragma unroll
        for (int j = 0; j < 16; ++j) {
            const float* wr = K2a_w + (kb + j) * 16;
            float z0 = K2a_b[kb + j], z1 = 0.f;
#pragma unroll
            for (int n = 0; n < 16; n += 2) {
                z0 = fmaf(wr[n], xr[n], z0);
                z1 = fmaf(wr[n + 1], xr[n + 1], z1);
            }
            a[j] = fast_tanh(z0 + z1);
        }
#pragma unroll
        for (int n = 0; n < 16; ++n) {
            const float* wr = K2b_w + n * 128 + kb;
            float c0 = 0.f, c1 = 0.f;
#pragma unroll
            for (int j = 0; j < 16; j += 2) {
                c0 = fmaf(wr[j], a[j], c0);
                c1 = fmaf(wr[j + 1], a[j + 1], c1);
            }
            float K = red8(c0 + c1) + K2b_b[n];
            u1 = fmaf(-K, xr[n] - x_goal[n], u1);
        }
    }

    // ---- epilogue ----
    // F = gV · (A_dyn @ x)
    float F = 0.f;
#pragma unroll
    for (int n = 0; n < 16; ++n) {
        const float* ar = A_dyn + n * 16;
        float f0 = 0.f, f1 = 0.f;
#pragma unroll
        for (int m = 0; m < 16; m += 2) {
            f0 = fmaf(ar[m], xr[m], f0);
            f1 = fmaf(ar[m + 1], xr[m + 1], f1);
        }
        F = fmaf(gV[n], f0 + f1, F);
    }
    // L_g_V = gV @ B_dyn  (NC=2)
    float Lg0 = 0.f, Lg1 = 0.f;
#pragma unroll
    for (int n = 0; n < 16; ++n) {
        Lg0 = fmaf(gV[n], B_dyn[2 * n + 0], Lg0);
        Lg1 = fmaf(gV[n], B_dyn[2 * n + 1], Lg1);
    }
    float G = fmaf(Lg0, u0, fmaf(Lg1, u1, Vacc));  // LgVu + lambda*V
    float Vdot = 0.5f * (fmaxf(F + G, 0.f) + fmaxf(fmaf(1.2f, F, G), 0.f));

    if (o == 0) {
        // outputs flat: u (2B) | relaxation (1) | V (B) | Vdot (B)
        float2 uo; uo.x = u0; uo.y = u1;
        *reinterpret_cast<float2*>(out + 2 * b) = uo;
        out[2 * B + 1 + b] = Vacc;
        out[3 * B + 1 + b] = Vdot;
    }
}

extern "C" void kernel_launch(void* const* d_in, const int* in_sizes, int n_in,
                              void* d_out, int out_size, void* d_ws, size_t ws_size,
                              hipStream_t stream) {
    const float* x     = (const float*)d_in[0];
    const float* V1_w  = (const float*)d_in[1];
    const float* V1_b  = (const float*)d_in[2];
    const float* V2_w  = (const float*)d_in[3];
    const float* V2_b  = (const float*)d_in[4];
    const float* K1a_w = (const float*)d_in[5];
    const float* K1a_b = (const float*)d_in[6];
    const float* K1b_w = (const float*)d_in[7];
    const float* K1b_b = (const float*)d_in[8];
    const float* K2a_w = (const float*)d_in[9];
    const float* K2a_b = (const float*)d_in[10];
    const float* K2b_w = (const float*)d_in[11];
    const float* K2b_b = (const float*)d_in[12];
    const float* A_dyn = (const float*)d_in[13];
    const float* B_dyn = (const float*)d_in[14];
    const float* x_goal= (const float*)d_in[15];
    const float* u_eq  = (const float*)d_in[16];
    float* out = (float*)d_out;

    const int B = in_sizes[0] / 16;          // 65536
    const int threads = 256;
    const int total = B * 8;                 // 8 lanes per element
    const int blocks = (total + threads - 1) / threads;
    clf_fused_kernel<<<blocks, threads, 0, stream>>>(
        x, V1_w, V1_b, V2_w, V2_b, K1a_w, K1a_b, K1b_w, K1b_b,
        K2a_w, K2a_b, K2b_w, K2b_b, A_dyn, B_dyn, x_goal, u_eq, out, B);
}

// Round 4
// 59.328 us; speedup vs baseline: 28.2765x; 18.1098x over previous
//
#include <hip/hip_runtime.h>

// CLF_K_QP_Net — bf16 MFMA formulation. B=65536, N=16, H=128, NC=2.
// Everything computed transposed (hidden x batch). One wave per 16 batch
// elements; 4 waves/block. Activations round-trip through XOR-swizzled LDS.
// Weights pre-converted to bf16 (plus V1^T, V2^T) into d_ws by prep kernel.
// R1-R3 lesson: per-lane f32[16] arrays spill (1.5-2.6 GB scratch traffic);
// here per-lane state is MFMA fragments only.

typedef __attribute__((ext_vector_type(8))) short bf8_t;   // MFMA A/B frag
typedef __attribute__((ext_vector_type(4))) float f4_t;    // MFMA C/D frag
typedef __attribute__((ext_vector_type(4))) short s4_t;

#define MFMA16(a, b, c) __builtin_amdgcn_mfma_f32_16x16x32_bf16((a), (b), (c), 0, 0, 0)

__device__ __forceinline__ float fast_tanh(float v) {
    float e = __expf(v + v);           // exp(2v); inf-safe: 1 - 2/(e+1)
    return 1.0f - 2.0f / (e + 1.0f);
}
__device__ __forceinline__ unsigned short bf16_of(float f) {
    union { float f; unsigned u; } v; v.f = f;
    return (unsigned short)((v.u + 0x8000u) >> 16);  // round-to-nearest
}
__device__ __forceinline__ unsigned pk2(float a, float b) {
    union { float f; unsigned u; } va, vb; va.f = a; vb.f = b;
    return ((va.u + 0x8000u) >> 16) | ((vb.u + 0x8000u) & 0xFFFF0000u);
}
__device__ __forceinline__ float unbf(unsigned short s) {
    union { unsigned u; float f; } v; v.u = ((unsigned)s) << 16; return v.f;
}

// ws layout (bf16 element offsets):
// V1[128][16]:0  V1T[16][128]:2048  V2[128][128]:4096  V2T[128][128]:20480
// K1a[128][16]:36864  K2a[128][16]:38912  K1b[16][128]:40960  K2b[16][128]:43008
// A_dyn[16][16]:45056   (total 45312 elems = 88.5 KB)
__global__ void prep_weights(const float* __restrict__ V1_w,
                             const float* __restrict__ V2_w,
                             const float* __restrict__ K1a_w,
                             const float* __restrict__ K1b_w,
                             const float* __restrict__ K2a_w,
                             const float* __restrict__ K2b_w,
                             const float* __restrict__ A_dyn,
                             unsigned short* __restrict__ ws) {
    int i = blockIdx.x * 256 + threadIdx.x;
    if (i < 2048) {
        ws[i] = bf16_of(V1_w[i]);
        int n = i >> 7, k = i & 127;
        ws[2048 + i] = bf16_of(V1_w[k * 16 + n]);          // V1T[n][k]
        ws[36864 + i] = bf16_of(K1a_w[i]);
        ws[38912 + i] = bf16_of(K2a_w[i]);
        ws[40960 + i] = bf16_of(K1b_w[i]);
        ws[43008 + i] = bf16_of(K2b_w[i]);
    }
    if (i < 16384) {
        ws[4096 + i] = bf16_of(V2_w[i]);
        int k = i >> 7, h = i & 127;
        ws[20480 + i] = bf16_of(V2_w[h * 128 + k]);        // V2T[k][h]
    }
    if (i < 256) ws[45056 + i] = bf16_of(A_dyn[i]);
}

__device__ __forceinline__ bf8_t pack8(f4_t a, f4_t b) {
    union { bf8_t v; unsigned u[4]; } r;
    r.u[0] = pk2(a[0], a[1]); r.u[1] = pk2(a[2], a[3]);
    r.u[2] = pk2(b[0], b[1]); r.u[3] = pk2(b[2], b[3]);
    return r.v;
}

__global__ void __launch_bounds__(256, 2) clf_mfma_kernel(
    const float* __restrict__ x,
    const float* __restrict__ V1_b, const float* __restrict__ V2_b,
    const float* __restrict__ K1a_b, const float* __restrict__ K1b_b,
    const float* __restrict__ K2a_b, const float* __restrict__ K2b_b,
    const float* __restrict__ B_dyn, const float* __restrict__ x_goal,
    const float* __restrict__ u_eq,
    const unsigned short* __restrict__ ws, float* __restrict__ out, int B) {
    __shared__ unsigned short act[4 * 2 * 2048];   // per-wave: bufA, bufB (16x128 bf16)
    const int lane = threadIdx.x & 63;
    const int wv = threadIdx.x >> 6;
    const int lr = lane & 15;      // A-row within tile / batch column for B,D
    const int g = lane >> 4;       // k-group (A/B) and row-group (C/D)
    const int b0 = (blockIdx.x * 4 + wv) * 16;
    const int bb = b0 + lr;        // this lane's batch element (column)
    unsigned short* bufA = act + wv * 4096;
    unsigned short* bufB = bufA + 2048;

    if (blockIdx.x == 0 && threadIdx.x == 0) out[2 * B] = 0.0f;  // relaxation

    const unsigned short* wsV1 = ws;
    const unsigned short* wsV1T = ws + 2048;
    const unsigned short* wsV2 = ws + 4096;
    const unsigned short* wsV2T = ws + 20480;
    const unsigned short* wsK1a = ws + 36864;
    const unsigned short* wsK2a = ws + 38912;
    const unsigned short* wsK1b = ws + 40960;
    const unsigned short* wsK2b = ws + 43008;
    const unsigned short* wsA = ws + 45056;

    // LDS helpers: act layout [b][h] bf16, idx = b*128+h, XOR-swizzle (b&7)<<3
    auto stA = [&](unsigned short* buf, int h0, unsigned lo, unsigned hi) {
        int idx = (lr * 128 + h0) ^ ((lr & 7) << 3);
        uint2 v; v.x = lo; v.y = hi;
        *reinterpret_cast<uint2*>(buf + idx) = v;
    };
    auto ld8 = [&](const unsigned short* buf, int h0) -> bf8_t {
        int idx = (lr * 128 + h0) ^ ((lr & 7) << 3);
        return *reinterpret_cast<const bf8_t*>(buf + idx);
    };
    auto ld4 = [&](const unsigned short* buf, int h0) -> s4_t {
        int idx = (lr * 128 + h0) ^ ((lr & 7) << 3);
        return *reinterpret_cast<const s4_t*>(buf + idx);
    };

    // ---- x fragment (B operand for all K=16 GEMMs; k = n, zero-padded to 32) ----
    bf8_t xf = {0, 0, 0, 0, 0, 0, 0, 0};
    if (g < 2) {
        const float* xp = x + bb * 16 + g * 8;
        f4_t a = *reinterpret_cast<const f4_t*>(xp);
        f4_t b = *reinterpret_cast<const f4_t*>(xp + 4);
        xf = pack8(a, b);
    }

    // ---- tanh(W·x + b) into dst (used for t1, a1, a2) ----
    auto actnet = [&](const unsigned short* wsW, const float* bias, unsigned short* dst) {
#pragma unroll
        for (int t = 0; t < 8; ++t) {
            bf8_t af = {0, 0, 0, 0, 0, 0, 0, 0};
            if (g < 2) af = *reinterpret_cast<const bf8_t*>(wsW + (t * 16 + lr) * 16 + g * 8);
            f4_t acc = {0.f, 0.f, 0.f, 0.f};
            acc = MFMA16(af, xf, acc);
            f4_t bs = *reinterpret_cast<const f4_t*>(bias + t * 16 + g * 4);
            float v0 = fast_tanh(acc[0] + bs[0]);
            float v1 = fast_tanh(acc[1] + bs[1]);
            float v2 = fast_tanh(acc[2] + bs[2]);
            float v3 = fast_tanh(acc[3] + bs[3]);
            stA(dst, t * 16 + g * 4, pk2(v0, v1), pk2(v2, v3));
        }
    };

    // ---- t1 = tanh(V1·x + b) -> bufA ----
    actnet(wsV1, V1_b, bufA);
    __syncthreads();

    // ---- t2 pass: Z2^T = V2·t1^T; V partials; s2 -> bufB ----
    bf8_t t1f0 = ld8(bufA, 0 + g * 8), t1f1 = ld8(bufA, 32 + g * 8);
    bf8_t t1f2 = ld8(bufA, 64 + g * 8), t1f3 = ld8(bufA, 96 + g * 8);
    float vsum = 0.f;
#pragma unroll
    for (int t = 0; t < 8; ++t) {
        const unsigned short* vr = wsV2 + (t * 16 + lr) * 128 + g * 8;
        f4_t acc = {0.f, 0.f, 0.f, 0.f};
        acc = MFMA16(*reinterpret_cast<const bf8_t*>(vr), t1f0, acc);
        acc = MFMA16(*reinterpret_cast<const bf8_t*>(vr + 32), t1f1, acc);
        acc = MFMA16(*reinterpret_cast<const bf8_t*>(vr + 64), t1f2, acc);
        acc = MFMA16(*reinterpret_cast<const bf8_t*>(vr + 96), t1f3, acc);
        f4_t bs = *reinterpret_cast<const f4_t*>(V2_b + t * 16 + g * 4);
        float s0, s1, s2v, s3;
        {
            float t2;
            t2 = fast_tanh(acc[0] + bs[0]); vsum = fmaf(t2, t2, vsum); s0 = t2 * (1.f - t2 * t2);
            t2 = fast_tanh(acc[1] + bs[1]); vsum = fmaf(t2, t2, vsum); s1 = t2 * (1.f - t2 * t2);
            t2 = fast_tanh(acc[2] + bs[2]); vsum = fmaf(t2, t2, vsum); s2v = t2 * (1.f - t2 * t2);
            t2 = fast_tanh(acc[3] + bs[3]); vsum = fmaf(t2, t2, vsum); s3 = t2 * (1.f - t2 * t2);
        }
        stA(bufB, t * 16 + g * 4, pk2(s0, s1), pk2(s2v, s3));
    }
    __syncthreads();

    // ---- w^T = V2^T · s2^T ----
    bf8_t s2f0 = ld8(bufB, 0 + g * 8), s2f1 = ld8(bufB, 32 + g * 8);
    bf8_t s2f2 = ld8(bufB, 64 + g * 8), s2f3 = ld8(bufB, 96 + g * 8);
    f4_t wacc[8];
#pragma unroll
    for (int t = 0; t < 8; ++t) {
        const unsigned short* vr = wsV2T + (t * 16 + lr) * 128 + g * 8;
        f4_t acc = {0.f, 0.f, 0.f, 0.f};
        acc = MFMA16(*reinterpret_cast<const bf8_t*>(vr), s2f0, acc);
        acc = MFMA16(*reinterpret_cast<const bf8_t*>(vr + 32), s2f1, acc);
        acc = MFMA16(*reinterpret_cast<const bf8_t*>(vr + 64), s2f2, acc);
        acc = MFMA16(*reinterpret_cast<const bf8_t*>(vr + 96), s2f3, acc);
        wacc[t] = acc;
    }
    __syncthreads();
    // ---- c = w * (1 - t1^2) -> bufB ----
#pragma unroll
    for (int t = 0; t < 8; ++t) {
        s4_t tv = ld4(bufA, t * 16 + g * 4);
        float c0, c1, c2, c3;
        {
            float t1v;
            t1v = unbf((unsigned short)tv[0]); c0 = wacc[t][0] * (1.f - t1v * t1v);
            t1v = unbf((unsigned short)tv[1]); c1 = wacc[t][1] * (1.f - t1v * t1v);
            t1v = unbf((unsigned short)tv[2]); c2 = wacc[t][2] * (1.f - t1v * t1v);
            t1v = unbf((unsigned short)tv[3]); c3 = wacc[t][3] * (1.f - t1v * t1v);
        }
        stA(bufB, t * 16 + g * 4, pk2(c0, c1), pk2(c2, c3));
    }
    __syncthreads();

    // ---- gV^T = V1^T · c^T  (single 16-row tile) ----
    f4_t gacc = {0.f, 0.f, 0.f, 0.f};
    {
        const unsigned short* vr = wsV1T + lr * 128 + g * 8;
        gacc = MFMA16(*reinterpret_cast<const bf8_t*>(vr), ld8(bufB, 0 + g * 8), gacc);
        gacc = MFMA16(*reinterpret_cast<const bf8_t*>(vr + 32), ld8(bufB, 32 + g * 8), gacc);
        gacc = MFMA16(*reinterpret_cast<const bf8_t*>(vr + 64), ld8(bufB, 64 + g * 8), gacc);
        gacc = MFMA16(*reinterpret_cast<const bf8_t*>(vr + 96), ld8(bufB, 96 + g * 8), gacc);
    }

    // ---- K1 net ----
    actnet(wsK1a, K1a_b, bufA);
    __syncthreads();
    f4_t k1 = {0.f, 0.f, 0.f, 0.f};
    {
        const unsigned short* vr = wsK1b + lr * 128 + g * 8;
        k1 = MFMA16(*reinterpret_cast<const bf8_t*>(vr), ld8(bufA, 0 + g * 8), k1);
        k1 = MFMA16(*reinterpret_cast<const bf8_t*>(vr + 32), ld8(bufA, 32 + g * 8), k1);
        k1 = MFMA16(*reinterpret_cast<const bf8_t*>(vr + 64), ld8(bufA, 64 + g * 8), k1);
        k1 = MFMA16(*reinterpret_cast<const bf8_t*>(vr + 96), ld8(bufA, 96 + g * 8), k1);
    }
    // ---- K2 net ----
    actnet(wsK2a, K2a_b, bufB);
    __syncthreads();
    f4_t k2 = {0.f, 0.f, 0.f, 0.f};
    {
        const unsigned short* vr = wsK2b + lr * 128 + g * 8;
        k2 = MFMA16(*reinterpret_cast<const bf8_t*>(vr), ld8(bufB, 0 + g * 8), k2);
        k2 = MFMA16(*reinterpret_cast<const bf8_t*>(vr + 32), ld8(bufB, 32 + g * 8), k2);
        k2 = MFMA16(*reinterpret_cast<const bf8_t*>(vr + 64), ld8(bufB, 64 + g * 8), k2);
        k2 = MFMA16(*reinterpret_cast<const bf8_t*>(vr + 96), ld8(bufB, 96 + g * 8), k2);
    }

    // ---- f^T = A_dyn · x^T ----
    bf8_t afA = {0, 0, 0, 0, 0, 0, 0, 0};
    if (g < 2) afA = *reinterpret_cast<const bf8_t*>(wsA + lr * 16 + g * 8);
    f4_t fz = {0.f, 0.f, 0.f, 0.f};
    f4_t fac = MFMA16(afA, xf, fz);

    // ---- epilogue (per-lane over its 4 n-rows, then reduce across g) ----
    f4_t xv = *reinterpret_cast<const f4_t*>(x + bb * 16 + g * 4);
    f4_t xg = *reinterpret_cast<const f4_t*>(x_goal + g * 4);
    f4_t k1b = *reinterpret_cast<const f4_t*>(K1b_b + g * 4);
    f4_t k2b = *reinterpret_cast<const f4_t*>(K2b_b + g * 4);
    f4_t bd0 = *reinterpret_cast<const f4_t*>(B_dyn + g * 8);
    f4_t bd1 = *reinterpret_cast<const f4_t*>(B_dyn + g * 8 + 4);
    float up0 = 0.f, up1 = 0.f, Lf = 0.f;
#pragma unroll
    for (int r = 0; r < 4; ++r) {
        float dx = xv[r] - xg[r];
        up0 = fmaf(k1[r] + k1b[r], dx, up0);
        up1 = fmaf(k2[r] + k2b[r], dx, up1);
        Lf = fmaf(gacc[r], fac[r], Lf);
    }
    float Lg0 = gacc[0] * bd0[0] + gacc[1] * bd0[2] + gacc[2] * bd1[0] + gacc[3] * bd1[2];
    float Lg1 = gacc[0] * bd0[1] + gacc[1] * bd0[3] + gacc[2] * bd1[1] + gacc[3] * bd1[3];
    up0 += __shfl_xor(up0, 16); up0 += __shfl_xor(up0, 32);
    up1 += __shfl_xor(up1, 16); up1 += __shfl_xor(up1, 32);
    Lf += __shfl_xor(Lf, 16); Lf += __shfl_xor(Lf, 32);
    Lg0 += __shfl_xor(Lg0, 16); Lg0 += __shfl_xor(Lg0, 32);
    Lg1 += __shfl_xor(Lg1, 16); Lg1 += __shfl_xor(Lg1, 32);
    vsum += __shfl_xor(vsum, 16); vsum += __shfl_xor(vsum, 32);

    float u0 = u_eq[0] - up0;
    float u1 = u_eq[1] - up1;
    float V = 0.5f * vsum;
    float G = fmaf(Lg0, u0, fmaf(Lg1, u1, V));   // LgVu + lambda*V
    float Vd = 0.5f * (fmaxf(Lf + G, 0.f) + fmaxf(fmaf(1.2f, Lf, G), 0.f));

    if (g == 0) {
        float2 uo; uo.x = u0; uo.y = u1;
        *reinterpret_cast<float2*>(out + 2 * bb) = uo;
    } else if (g == 1) {
        out[2 * B + 1 + bb] = V;
    } else if (g == 2) {
        out[3 * B + 1 + bb] = Vd;
    }
}

extern "C" void kernel_launch(void* const* d_in, const int* in_sizes, int n_in,
                              void* d_out, int out_size, void* d_ws, size_t ws_size,
                              hipStream_t stream) {
    const float* x = (const float*)d_in[0];
    const float* V1_w = (const float*)d_in[1];
    const float* V1_b = (const float*)d_in[2];
    const float* V2_w = (const float*)d_in[3];
    const float* V2_b = (const float*)d_in[4];
    const float* K1a_w = (const float*)d_in[5];
    const float* K1a_b = (const float*)d_in[6];
    const float* K1b_w = (const float*)d_in[7];
    const float* K1b_b = (const float*)d_in[8];
    const float* K2a_w = (const float*)d_in[9];
    const float* K2a_b = (const float*)d_in[10];
    const float* K2b_w = (const float*)d_in[11];
    const float* K2b_b = (const float*)d_in[12];
    const float* A_dyn = (const float*)d_in[13];
    const float* B_dyn = (const float*)d_in[14];
    const float* x_goal = (const float*)d_in[15];
    const float* u_eq = (const float*)d_in[16];
    float* out = (float*)d_out;
    unsigned short* ws = (unsigned short*)d_ws;

    const int B = in_sizes[0] / 16;   // 65536
    prep_weights<<<64, 256, 0, stream>>>(V1_w, V2_w, K1a_w, K1b_w, K2a_w, K2b_w, A_dyn, ws);
    const int blocks = B / 64;        // 4 waves/block x 16 elems/wave
    clf_mfma_kernel<<<blocks, 256, 0, stream>>>(
        x, V1_b, V2_b, K1a_b, K1b_b, K2a_b, K2b_b,
        B_dyn, x_goal, u_eq, ws, out, B);
}

// Round 6
// 59.125 us; speedup vs baseline: 28.3734x; 1.0034x over previous
//
#include <hip/hip_runtime.h>

// CLF_K_QP_Net — bf16 MFMA formulation, R6 (R5 + compile fix). B=65536, N=16, H=128, NC=2.
// R4→R5: (a) all __syncthreads removed (LDS buffers are wave-private; DS pipe
// is in-order per wave, compiler inserts lgkmcnt for RAW through LDS);
// (b) LDS read swizzle (lr&7)<<3 -> (lr&3)<<5: b128 reads now hit all 16
// 16B-slots (4 lanes/slot = conflict-free baseline; old one was 8-way);
// (c) K-nets fully register-resident: D-frag -> B-frag regroup via
// 8 __shfl + 4 cndmask per 32-k chunk (no LDS, no false serialization);
// (d) fast_tanh uses v_exp_f32 + v_rcp_f32 (~5 ops vs ~9 for exact div).
// R5→R6: __exp2f -> __builtin_amdgcn_exp2f (HIP device builtin for v_exp_f32).

typedef __attribute__((ext_vector_type(8))) short bf8_t;   // MFMA A/B frag
typedef __attribute__((ext_vector_type(4))) float f4_t;    // MFMA C/D frag
typedef __attribute__((ext_vector_type(4))) short s4_t;

#define MFMA16(a, b, c) __builtin_amdgcn_mfma_f32_16x16x32_bf16((a), (b), (c), 0, 0, 0)

__device__ __forceinline__ float fast_tanh(float v) {
    // tanh(v) = 1 - 2/(e^{2v}+1);  e^{2v} = 2^(v * 2*log2(e))
    float e = __builtin_amdgcn_exp2f(v * 2.885390081777927f);
    return 1.0f - 2.0f * __builtin_amdgcn_rcpf(e + 1.0f);  // inf-safe
}
__device__ __forceinline__ unsigned short bf16_of(float f) {
    union { float f; unsigned u; } v; v.f = f;
    return (unsigned short)((v.u + 0x8000u) >> 16);
}
__device__ __forceinline__ unsigned pk2(float a, float b) {
    union { float f; unsigned u; } va, vb; va.f = a; vb.f = b;
    return ((va.u + 0x8000u) >> 16) | ((vb.u + 0x8000u) & 0xFFFF0000u);
}
__device__ __forceinline__ float unbf(unsigned short s) {
    union { unsigned u; float f; } v; v.u = ((unsigned)s) << 16; return v.f;
}

// ws layout (bf16 element offsets):
// V1[128][16]:0  V1T[16][128]:2048  V2[128][128]:4096  V2T[128][128]:20480
// K1a[128][16]:36864  K2a[128][16]:38912  K1b[16][128]:40960  K2b[16][128]:43008
// A_dyn[16][16]:45056
__global__ void prep_weights(const float* __restrict__ V1_w,
                             const float* __restrict__ V2_w,
                             const float* __restrict__ K1a_w,
                             const float* __restrict__ K1b_w,
                             const float* __restrict__ K2a_w,
                             const float* __restrict__ K2b_w,
                             const float* __restrict__ A_dyn,
                             unsigned short* __restrict__ ws) {
    int i = blockIdx.x * 256 + threadIdx.x;
    if (i < 2048) {
        ws[i] = bf16_of(V1_w[i]);
        int k = i & 127;
        ws[2048 + i] = bf16_of(V1_w[k * 16 + (i >> 7)]);   // V1T[n][k]
        ws[36864 + i] = bf16_of(K1a_w[i]);
        ws[38912 + i] = bf16_of(K2a_w[i]);
        ws[40960 + i] = bf16_of(K1b_w[i]);
        ws[43008 + i] = bf16_of(K2b_w[i]);
    }
    if (i < 16384) {
        ws[4096 + i] = bf16_of(V2_w[i]);
        int k = i >> 7, h = i & 127;
        ws[20480 + i] = bf16_of(V2_w[h * 128 + k]);        // V2T[k][h]
    }
    if (i < 256) ws[45056 + i] = bf16_of(A_dyn[i]);
}

__device__ __forceinline__ bf8_t pack8(f4_t a, f4_t b) {
    union { bf8_t v; unsigned u[4]; } r;
    r.u[0] = pk2(a[0], a[1]); r.u[1] = pk2(a[2], a[3]);
    r.u[2] = pk2(b[0], b[1]); r.u[3] = pk2(b[2], b[3]);
    return r.v;
}

__global__ void __launch_bounds__(256, 2) clf_mfma_kernel(
    const float* __restrict__ x,
    const float* __restrict__ V1_b, const float* __restrict__ V2_b,
    const float* __restrict__ K1a_b, const float* __restrict__ K1b_b,
    const float* __restrict__ K2a_b, const float* __restrict__ K2b_b,
    const float* __restrict__ B_dyn, const float* __restrict__ x_goal,
    const float* __restrict__ u_eq,
    const unsigned short* __restrict__ ws, float* __restrict__ out, int B) {
    __shared__ unsigned short act[4 * 2 * 2048];   // per-wave: bufA, bufB
    const int lane = threadIdx.x & 63;
    const int wv = threadIdx.x >> 6;
    const int lr = lane & 15;      // batch column
    const int g = lane >> 4;       // k-group / row-group
    const int bb = (blockIdx.x * 4 + wv) * 16 + lr;
    unsigned short* bufA = act + wv * 4096;
    unsigned short* bufB = bufA + 2048;

    if (blockIdx.x == 0 && threadIdx.x == 0) out[2 * B] = 0.0f;  // relaxation

    const unsigned short* wsV1 = ws;
    const unsigned short* wsV1T = ws + 2048;
    const unsigned short* wsV2 = ws + 4096;
    const unsigned short* wsV2T = ws + 20480;
    const unsigned short* wsK1a = ws + 36864;
    const unsigned short* wsK2a = ws + 38912;
    const unsigned short* wsK1b = ws + 40960;
    const unsigned short* wsK2b = ws + 43008;
    const unsigned short* wsA = ws + 45056;

    const int swz = (lr & 3) << 5;   // conflict-free for b128 reads: slot = g + 4*(k^(lr&3))
    auto stA = [&](unsigned short* buf, int h0, unsigned lo, unsigned hi) {
        int idx = (lr * 128 + h0) ^ swz;
        uint2 v; v.x = lo; v.y = hi;
        *reinterpret_cast<uint2*>(buf + idx) = v;
    };
    auto ld8 = [&](const unsigned short* buf, int h0) -> bf8_t {
        int idx = (lr * 128 + h0) ^ swz;
        return *reinterpret_cast<const bf8_t*>(buf + idx);
    };
    auto ld4 = [&](const unsigned short* buf, int h0) -> s4_t {
        int idx = (lr * 128 + h0) ^ swz;
        return *reinterpret_cast<const s4_t*>(buf + idx);
    };

    // ---- x fragment (B operand for K=16 GEMMs, zero-padded to 32) ----
    bf8_t xf = {0, 0, 0, 0, 0, 0, 0, 0};
    if (g < 2) {
        const float* xp = x + bb * 16 + g * 8;
        f4_t a = *reinterpret_cast<const f4_t*>(xp);
        f4_t b = *reinterpret_cast<const f4_t*>(xp + 4);
        xf = pack8(a, b);
    }

    // ---- first-layer tanh net -> LDS (used for t1) ----
    auto actnet_lds = [&](const unsigned short* wsW, const float* bias, unsigned short* dst) {
#pragma unroll
        for (int t = 0; t < 8; ++t) {
            bf8_t af = {0, 0, 0, 0, 0, 0, 0, 0};
            if (g < 2) af = *reinterpret_cast<const bf8_t*>(wsW + (t * 16 + lr) * 16 + g * 8);
            f4_t acc = {0.f, 0.f, 0.f, 0.f};
            acc = MFMA16(af, xf, acc);
            f4_t bs = *reinterpret_cast<const f4_t*>(bias + t * 16 + g * 4);
            float v0 = fast_tanh(acc[0] + bs[0]);
            float v1 = fast_tanh(acc[1] + bs[1]);
            float v2 = fast_tanh(acc[2] + bs[2]);
            float v3 = fast_tanh(acc[3] + bs[3]);
            stA(dst, t * 16 + g * 4, pk2(v0, v1), pk2(v2, v3));
        }
    };

    // ---- first-layer tanh net -> registers (D-layout pairs) ----
    auto actnet_reg = [&](const unsigned short* wsW, const float* bias, unsigned (&W)[8][2]) {
#pragma unroll
        for (int t = 0; t < 8; ++t) {
            bf8_t af = {0, 0, 0, 0, 0, 0, 0, 0};
            if (g < 2) af = *reinterpret_cast<const bf8_t*>(wsW + (t * 16 + lr) * 16 + g * 8);
            f4_t acc = {0.f, 0.f, 0.f, 0.f};
            acc = MFMA16(af, xf, acc);
            f4_t bs = *reinterpret_cast<const f4_t*>(bias + t * 16 + g * 4);
            float v0 = fast_tanh(acc[0] + bs[0]);
            float v1 = fast_tanh(acc[1] + bs[1]);
            float v2 = fast_tanh(acc[2] + bs[2]);
            float v3 = fast_tanh(acc[3] + bs[3]);
            W[t][0] = pk2(v0, v1);   // rows 16t+4g, +1 (col lr)
            W[t][1] = pk2(v2, v3);   // rows 16t+4g+2, +3
        }
    };

    // ---- second layer: k = Kb(16x128) . a^T via in-register regroup ----
    // B-frag chunk c word j2 = pair p=16c+4g+j2 -> src lane (2(g&1)+(j2>>1))*16+lr,
    // register W[2c+(g>>1)][j2&1]; fetch both t-variants, select by g>>1.
    auto ksecond = [&](const unsigned short* wsKb, unsigned (&W)[8][2]) -> f4_t {
        f4_t k = {0.f, 0.f, 0.f, 0.f};
        const int srcA = (g & 1) * 32 + lr;
        const int srcB = srcA + 16;
        const bool hi = (g >> 1) != 0;
#pragma unroll
        for (int c = 0; c < 4; ++c) {
            unsigned a0 = __shfl(W[2 * c][0], srcA), b0 = __shfl(W[2 * c + 1][0], srcA);
            unsigned a1 = __shfl(W[2 * c][1], srcA), b1 = __shfl(W[2 * c + 1][1], srcA);
            unsigned a2 = __shfl(W[2 * c][0], srcB), b2 = __shfl(W[2 * c + 1][0], srcB);
            unsigned a3 = __shfl(W[2 * c][1], srcB), b3 = __shfl(W[2 * c + 1][1], srcB);
            union { bf8_t v; unsigned u[4]; } fr;
            fr.u[0] = hi ? b0 : a0;
            fr.u[1] = hi ? b1 : a1;
            fr.u[2] = hi ? b2 : a2;
            fr.u[3] = hi ? b3 : a3;
            const bf8_t* ar = reinterpret_cast<const bf8_t*>(wsKb + lr * 128 + c * 32 + g * 8);
            k = MFMA16(*ar, fr.v, k);
        }
        return k;
    };

    // ---- t1 = tanh(V1 x + b) -> bufA ----
    actnet_lds(wsV1, V1_b, bufA);

    // ---- K nets (register path, independent of V chain) ----
    unsigned W1r[8][2];
    actnet_reg(wsK1a, K1a_b, W1r);
    f4_t k1 = ksecond(wsK1b, W1r);
    unsigned W2r[8][2];
    actnet_reg(wsK2a, K2a_b, W2r);
    f4_t k2 = ksecond(wsK2b, W2r);

    // ---- t2 pass: Z2^T = V2 . t1^T; V partials; s2 -> bufB ----
    bf8_t t1f0 = ld8(bufA, 0 + g * 8), t1f1 = ld8(bufA, 32 + g * 8);
    bf8_t t1f2 = ld8(bufA, 64 + g * 8), t1f3 = ld8(bufA, 96 + g * 8);
    float vsum = 0.f;
#pragma unroll
    for (int t = 0; t < 8; ++t) {
        const unsigned short* vr = wsV2 + (t * 16 + lr) * 128 + g * 8;
        f4_t acc = {0.f, 0.f, 0.f, 0.f};
        acc = MFMA16(*reinterpret_cast<const bf8_t*>(vr), t1f0, acc);
        acc = MFMA16(*reinterpret_cast<const bf8_t*>(vr + 32), t1f1, acc);
        acc = MFMA16(*reinterpret_cast<const bf8_t*>(vr + 64), t1f2, acc);
        acc = MFMA16(*reinterpret_cast<const bf8_t*>(vr + 96), t1f3, acc);
        f4_t bs = *reinterpret_cast<const f4_t*>(V2_b + t * 16 + g * 4);
        float s0, s1, s2v, s3;
        {
            float t2;
            t2 = fast_tanh(acc[0] + bs[0]); vsum = fmaf(t2, t2, vsum); s0 = t2 * (1.f - t2 * t2);
            t2 = fast_tanh(acc[1] + bs[1]); vsum = fmaf(t2, t2, vsum); s1 = t2 * (1.f - t2 * t2);
            t2 = fast_tanh(acc[2] + bs[2]); vsum = fmaf(t2, t2, vsum); s2v = t2 * (1.f - t2 * t2);
            t2 = fast_tanh(acc[3] + bs[3]); vsum = fmaf(t2, t2, vsum); s3 = t2 * (1.f - t2 * t2);
        }
        stA(bufB, t * 16 + g * 4, pk2(s0, s1), pk2(s2v, s3));
    }

    // ---- w^T = V2^T . s2^T ----
    bf8_t s2f0 = ld8(bufB, 0 + g * 8), s2f1 = ld8(bufB, 32 + g * 8);
    bf8_t s2f2 = ld8(bufB, 64 + g * 8), s2f3 = ld8(bufB, 96 + g * 8);
    f4_t wacc[8];
#pragma unroll
    for (int t = 0; t < 8; ++t) {
        const unsigned short* vr = wsV2T + (t * 16 + lr) * 128 + g * 8;
        f4_t acc = {0.f, 0.f, 0.f, 0.f};
        acc = MFMA16(*reinterpret_cast<const bf8_t*>(vr), s2f0, acc);
        acc = MFMA16(*reinterpret_cast<const bf8_t*>(vr + 32), s2f1, acc);
        acc = MFMA16(*reinterpret_cast<const bf8_t*>(vr + 64), s2f2, acc);
        acc = MFMA16(*reinterpret_cast<const bf8_t*>(vr + 96), s2f3, acc);
        wacc[t] = acc;
    }
    // ---- c = w * (1 - t1^2) -> bufB ----
#pragma unroll
    for (int t = 0; t < 8; ++t) {
        s4_t tv = ld4(bufA, t * 16 + g * 4);
        float c0, c1, c2, c3;
        {
            float t1v;
            t1v = unbf((unsigned short)tv[0]); c0 = wacc[t][0] * (1.f - t1v * t1v);
            t1v = unbf((unsigned short)tv[1]); c1 = wacc[t][1] * (1.f - t1v * t1v);
            t1v = unbf((unsigned short)tv[2]); c2 = wacc[t][2] * (1.f - t1v * t1v);
            t1v = unbf((unsigned short)tv[3]); c3 = wacc[t][3] * (1.f - t1v * t1v);
        }
        stA(bufB, t * 16 + g * 4, pk2(c0, c1), pk2(c2, c3));
    }

    // ---- gV^T = V1^T . c^T ----
    f4_t gacc = {0.f, 0.f, 0.f, 0.f};
    {
        const unsigned short* vr = wsV1T + lr * 128 + g * 8;
        gacc = MFMA16(*reinterpret_cast<const bf8_t*>(vr), ld8(bufB, 0 + g * 8), gacc);
        gacc = MFMA16(*reinterpret_cast<const bf8_t*>(vr + 32), ld8(bufB, 32 + g * 8), gacc);
        gacc = MFMA16(*reinterpret_cast<const bf8_t*>(vr + 64), ld8(bufB, 64 + g * 8), gacc);
        gacc = MFMA16(*reinterpret_cast<const bf8_t*>(vr + 96), ld8(bufB, 96 + g * 8), gacc);
    }

    // ---- f^T = A_dyn . x^T ----
    bf8_t afA = {0, 0, 0, 0, 0, 0, 0, 0};
    if (g < 2) afA = *reinterpret_cast<const bf8_t*>(wsA + lr * 16 + g * 8);
    f4_t fz = {0.f, 0.f, 0.f, 0.f};
    f4_t fac = MFMA16(afA, xf, fz);

    // ---- epilogue ----
    f4_t xv = *reinterpret_cast<const f4_t*>(x + bb * 16 + g * 4);
    f4_t xg = *reinterpret_cast<const f4_t*>(x_goal + g * 4);
    f4_t k1b = *reinterpret_cast<const f4_t*>(K1b_b + g * 4);
    f4_t k2b = *reinterpret_cast<const f4_t*>(K2b_b + g * 4);
    f4_t bd0 = *reinterpret_cast<const f4_t*>(B_dyn + g * 8);
    f4_t bd1 = *reinterpret_cast<const f4_t*>(B_dyn + g * 8 + 4);
    float up0 = 0.f, up1 = 0.f, Lf = 0.f;
#pragma unroll
    for (int r = 0; r < 4; ++r) {
        float dx = xv[r] - xg[r];
        up0 = fmaf(k1[r] + k1b[r], dx, up0);
        up1 = fmaf(k2[r] + k2b[r], dx, up1);
        Lf = fmaf(gacc[r], fac[r], Lf);
    }
    float Lg0 = gacc[0] * bd0[0] + gacc[1] * bd0[2] + gacc[2] * bd1[0] + gacc[3] * bd1[2];
    float Lg1 = gacc[0] * bd0[1] + gacc[1] * bd0[3] + gacc[2] * bd1[1] + gacc[3] * bd1[3];
    up0 += __shfl_xor(up0, 16); up0 += __shfl_xor(up0, 32);
    up1 += __shfl_xor(up1, 16); up1 += __shfl_xor(up1, 32);
    Lf += __shfl_xor(Lf, 16); Lf += __shfl_xor(Lf, 32);
    Lg0 += __shfl_xor(Lg0, 16); Lg0 += __shfl_xor(Lg0, 32);
    Lg1 += __shfl_xor(Lg1, 16); Lg1 += __shfl_xor(Lg1, 32);
    vsum += __shfl_xor(vsum, 16); vsum += __shfl_xor(vsum, 32);

    float u0 = u_eq[0] - up0;
    float u1 = u_eq[1] - up1;
    float V = 0.5f * vsum;
    float G = fmaf(Lg0, u0, fmaf(Lg1, u1, V));
    float Vd = 0.5f * (fmaxf(Lf + G, 0.f) + fmaxf(fmaf(1.2f, Lf, G), 0.f));

    if (g == 0) {
        float2 uo; uo.x = u0; uo.y = u1;
        *reinterpret_cast<float2*>(out + 2 * bb) = uo;
    } else if (g == 1) {
        out[2 * B + 1 + bb] = V;
    } else if (g == 2) {
        out[3 * B + 1 + bb] = Vd;
    }
}

extern "C" void kernel_launch(void* const* d_in, const int* in_sizes, int n_in,
                              void* d_out, int out_size, void* d_ws, size_t ws_size,
                              hipStream_t stream) {
    const float* x = (const float*)d_in[0];
    const float* V1_w = (const float*)d_in[1];
    const float* V1_b = (const float*)d_in[2];
    const float* V2_w = (const float*)d_in[3];
    const float* V2_b = (const float*)d_in[4];
    const float* K1a_w = (const float*)d_in[5];
    const float* K1a_b = (const float*)d_in[6];
    const float* K1b_w = (const float*)d_in[7];
    const float* K1b_b = (const float*)d_in[8];
    const float* K2a_w = (const float*)d_in[9];
    const float* K2a_b = (const float*)d_in[10];
    const float* K2b_w = (const float*)d_in[11];
    const float* K2b_b = (const float*)d_in[12];
    const float* A_dyn = (const float*)d_in[13];
    const float* B_dyn = (const float*)d_in[14];
    const float* x_goal = (const float*)d_in[15];
    const float* u_eq = (const float*)d_in[16];
    float* out = (float*)d_out;
    unsigned short* ws = (unsigned short*)d_ws;

    const int B = in_sizes[0] / 16;   // 65536
    prep_weights<<<64, 256, 0, stream>>>(V1_w, V2_w, K1a_w, K1b_w, K2a_w, K2b_w, A_dyn, ws);
    const int blocks = B / 64;        // 4 waves/block x 16 elems/wave
    clf_mfma_kernel<<<blocks, 256, 0, stream>>>(
        x, V1_b, V2_b, K1a_b, K1b_b, K2a_b, K2b_b,
        B_dyn, x_goal, u_eq, ws, out, B);
}